// Round 6
// baseline (342.857 us; speedup 1.0000x reference)
//
#include <hip/hip_runtime.h>
#include <hip/hip_bf16.h>

using bf16 = __bf16;
using bf16x8 = __attribute__((ext_vector_type(8))) __bf16;
using bf16x4 = __attribute__((ext_vector_type(4))) __bf16;
using f32x4  = __attribute__((ext_vector_type(4))) float;

typedef const void __attribute__((address_space(1)))* gas_p;
typedef void __attribute__((address_space(3)))* las_p;

#define GLD16(g, l) __builtin_amdgcn_global_load_lds((gas_p)(const void*)(g), (las_p)(void*)(l), 16, 0, 0)

__device__ __forceinline__ bf16x8 lds_ld8(const void* p) {
  union { uint4 u; bf16x8 v; } c;
  c.u = *(const uint4*)p;
  return c.v;
}
__device__ __forceinline__ bf16x8 g_ld8(const bf16* p) {
  union { uint4 u; bf16x8 v; } c;
  c.u = *(const uint4*)p;
  return c.v;
}
// single-instruction 2^x
__device__ __forceinline__ float fexp2(float x) {
  float r; asm("v_exp_f32 %0, %1" : "=v"(r) : "v"(x)); return r;
}
// pack 4 f32 -> 4 bf16 in a uint2 (memory order p0,p1,p2,p3)
__device__ __forceinline__ uint2 pack4(float p0, float p1, float p2, float p3) {
  union { bf16 h[4]; uint2 u; } c;
  c.h[0] = (bf16)p0; c.h[1] = (bf16)p1; c.h[2] = (bf16)p2; c.h[3] = (bf16)p3;
  return c.u;
}

// ---------------- f32 -> bf16 elementwise convert ----------------
__global__ void k_convert(const float* __restrict__ in, bf16* __restrict__ out, int n4) {
  int i = blockIdx.x * blockDim.x + threadIdx.x;
  if (i >= n4) return;
  float4 f = ((const float4*)in)[i];
  bf16x4 o;
  o[0] = (bf16)f.x; o[1] = (bf16)f.y; o[2] = (bf16)f.z; o[3] = (bf16)f.w;
  ((bf16x4*)out)[i] = o;
}

// ---------------- transpose + convert weights: W[K=2048][N] -> Wt[N][2048] bf16 ----------------
__global__ void k_transp(const float* __restrict__ W, bf16* __restrict__ Wt, int N, int rowOff) {
  __shared__ float tile[64][65];
  const int n0 = blockIdx.x * 64, k0 = blockIdx.y * 64;
  const int t = threadIdx.x;
#pragma unroll
  for (int i = 0; i < 16; ++i) {
    int idx = t + i * 256; int r = idx >> 6, c = idx & 63;
    tile[r][c] = W[(size_t)(k0 + r) * N + n0 + c];
  }
  __syncthreads();
#pragma unroll
  for (int i = 0; i < 16; ++i) {
    int idx = t + i * 256; int r = idx >> 6, c = idx & 63;
    Wt[(size_t)(rowOff + n0 + r) * 2048 + k0 + c] = (bf16)tile[c][r];
  }
}

// ---------------- GEMM main loop: C[128x128] += A[128xK] * Bt[128xK]^T, K=2048, BK=32 ----------------
__device__ __forceinline__ void gemm_main(const bf16* __restrict__ A, const bf16* __restrict__ Bt,
                                          int brow, int bcol, int tid, f32x4 (&acc)[4][4],
                                          char* ldsA, char* ldsB) {
  const int lane = tid & 63;
  const int l15 = lane & 15, l4 = lane >> 4;
  const int wid = tid >> 6, wr = wid >> 1, wc = wid & 1;
  const int srow = tid >> 2;
  const int sseg = (tid & 3) ^ (srow & 3);   // pre-swizzled global source (m173 pattern)
  const bf16* ga = A  + (size_t)(brow + srow) * 2048 + sseg * 8;
  const bf16* gb = Bt + (size_t)(bcol + srow) * 2048 + sseg * 8;
  char* la = ldsA + tid * 16;
  char* lb = ldsB + tid * 16;
  const int roff = (l15 & 3) << 4;

  for (int k0 = 0; k0 < 2048; k0 += 32) {
    __syncthreads();
    GLD16(ga + k0, la);
    GLD16(ga + k0 + (size_t)64 * 2048, la + 4096);
    GLD16(gb + k0, lb);
    GLD16(gb + k0 + (size_t)64 * 2048, lb + 4096);
    __syncthreads();
    bf16x8 af[4], bfr[4];
#pragma unroll
    for (int m = 0; m < 4; ++m)
      af[m] = lds_ld8(ldsA + (wr * 64 + m * 16 + l15) * 64 + ((l4 << 4) ^ roff));
#pragma unroll
    for (int n = 0; n < 4; ++n)
      bfr[n] = lds_ld8(ldsB + (wc * 64 + n * 16 + l15) * 64 + ((l4 << 4) ^ roff));
#pragma unroll
    for (int m = 0; m < 4; ++m)
#pragma unroll
      for (int n = 0; n < 4; ++n)
        acc[m][n] = __builtin_amdgcn_mfma_f32_16x16x32_bf16(af[m], bfr[n], acc[m][n], 0, 0, 0);
  }
}

// ---------------- QKV GEMM + RoPE epilogue (V written transposed) ----------------
// Q scale folds 1/sqrt(64) * log2(e) so attention softmax can use exp2 directly.
__global__ __launch_bounds__(256) void k_gemm_qkv(const bf16* __restrict__ A, const bf16* __restrict__ Bt,
    const float* __restrict__ cosT, const float* __restrict__ sinT,
    bf16* __restrict__ Qb, bf16* __restrict__ Kb, bf16* __restrict__ Vt) {
  __shared__ __align__(16) char ldsA[8192];
  __shared__ __align__(16) char ldsB[8192];
  const int tid = threadIdx.x;
  const int brow = blockIdx.x * 128, bcol = blockIdx.y * 128;
  f32x4 zero = {0.f, 0.f, 0.f, 0.f};
  f32x4 acc[4][4];
#pragma unroll
  for (int m = 0; m < 4; ++m)
#pragma unroll
    for (int n = 0; n < 4; ++n) acc[m][n] = zero;

  gemm_main(A, Bt, brow, bcol, tid, acc, ldsA, ldsB);

  const int lane = tid & 63, l15 = lane & 15, l4 = lane >> 4;
  const int wid = tid >> 6, wr = wid >> 1, wc = wid & 1;
  const int base64 = bcol + wc * 64;       // wave-uniform; one head per wave block
  const int rbase  = brow + wr * 64;

  if (base64 < 2048) {                      // Q segment (RoPE + 0.125*log2e scale)
    const int h = base64 >> 6;
#pragma unroll
    for (int m = 0; m < 4; ++m)
#pragma unroll
      for (int r = 0; r < 4; ++r) {
        const int row = rbase + m * 16 + l4 * 4 + r;
        const int b = row >> 11, s = row & 2047;
        float o[4];
#pragma unroll
        for (int n = 0; n < 4; ++n) {
          const int d = n * 16 + l15;
          const float cv = cosT[s * 64 + d], sv = sinT[s * 64 + d];
          const float t = acc[m][n][r], p = acc[m][n ^ 2][r];
          o[n] = (t * cv + ((n < 2) ? -p : p) * sv) * 0.18033688f;
        }
        bf16* dst = Qb + ((size_t)((b * 32 + h) * 2048 + s)) * 64;
#pragma unroll
        for (int n = 0; n < 4; ++n) dst[n * 16 + l15] = (bf16)o[n];
      }
  } else if (base64 < 2560) {               // K segment (RoPE)
    const int h = (base64 - 2048) >> 6;
#pragma unroll
    for (int m = 0; m < 4; ++m)
#pragma unroll
      for (int r = 0; r < 4; ++r) {
        const int row = rbase + m * 16 + l4 * 4 + r;
        const int b = row >> 11, s = row & 2047;
        float o[4];
#pragma unroll
        for (int n = 0; n < 4; ++n) {
          const int d = n * 16 + l15;
          const float cv = cosT[s * 64 + d], sv = sinT[s * 64 + d];
          const float t = acc[m][n][r], p = acc[m][n ^ 2][r];
          o[n] = t * cv + ((n < 2) ? -p : p) * sv;
        }
        bf16* dst = Kb + ((size_t)((b * 8 + h) * 2048 + s)) * 64;
#pragma unroll
        for (int n = 0; n < 4; ++n) dst[n * 16 + l15] = (bf16)o[n];
      }
  } else {                                  // V segment -> transposed Vt[b][hk][d][s]
    const int h = (base64 - 2560) >> 6;
#pragma unroll
    for (int m = 0; m < 4; ++m)
#pragma unroll
      for (int r = 0; r < 4; ++r) {
        const int row = rbase + m * 16 + l4 * 4 + r;
        const int b = row >> 11, s = row & 2047;
#pragma unroll
        for (int n = 0; n < 4; ++n) {
          const int d = n * 16 + l15;
          Vt[((size_t)((b * 8 + h) * 64 + d)) * 2048 + s] = (bf16)acc[m][n][r];
        }
      }
  }
}

// ---------------- Flash attention (causal, GQA), split-K across the 4 waves ----------------
// One block per (chunk, bh): chunk = 32 q rows; wave w handles kv tiles
// kt = w, w+4, ...; private online-softmax state; 2-round LDS merge at the end.
// Low-VGPR design (__launch_bounds__(256,4)) targets 16 waves/CU.
__global__ __launch_bounds__(256, 4) void k_attn(const bf16* __restrict__ Qb, const bf16* __restrict__ Kb,
                                                 const bf16* __restrict__ Vt, bf16* __restrict__ ctx) {
  __shared__ __align__(16) char lds[18432];   // loop: 4 waves x 4KB P; merge: 2 slots x 9216B
  const int tid = threadIdx.x, lane = tid & 63, w = tid >> 6;
  const int l15 = lane & 15, l4 = lane >> 4;
  // XCD-aware decode: XCD = p&7 owns bh in [8*xcd, 8*xcd+8); heavy chunks first
  const int p = (int)blockIdx.x;
  const int qq = p >> 3;
  const int y = (p & 7) * 8 + (qq & 7);        // bh
  const int c = 63 - (qq >> 3);                // chunk, heavy dispatched first
  const int q0 = c * 32, nf = c >> 1;
  const int b = y >> 5, h = y & 31, hk = h >> 2;
  const int sw = (l15 & 7) << 4;
  char* plw = lds + w * 4096;                  // per-wave P: 2 mi x 2KB
  float (*mb)[2][18][64] = (float (*)[2][18][64])lds;

  const bf16* kg = Kb + ((size_t)((b * 8 + hk) * 2048)) * 64 + l15 * 64 + l4 * 8;
  const bf16* vg = Vt + ((size_t)((b * 8 + hk) * 64)) * 2048 + l15 * 2048 + l4 * 8;
  const bf16* qg = Qb + ((size_t)((b * 32 + h) * 2048) + q0) * 64;

  const f32x4 zero = {0.f, 0.f, 0.f, 0.f};
  bf16x8 bq[2][2];
#pragma unroll
  for (int mi = 0; mi < 2; ++mi)
#pragma unroll
    for (int kk = 0; kk < 2; ++kk)
      bq[mi][kk] = g_ld8(qg + (mi * 16 + l15) * 64 + kk * 32 + l4 * 8);
  f32x4 o[2][4];
#pragma unroll
  for (int mi = 0; mi < 2; ++mi)
#pragma unroll
    for (int n = 0; n < 4; ++n) o[mi][n] = zero;
  float m[2] = {-3.0e38f, -3.0e38f};
  float l[2] = {0.f, 0.f};

  for (int kt = w; kt <= nf; kt += 4) {
    const int kv0 = kt * 64;
    // ---- K fragments; dead after QK so av can reuse the registers ----
    bf16x8 kb[4][2];
    const bf16* kp = kg + (size_t)kt * 4096;
#pragma unroll
    for (int n = 0; n < 4; ++n)
#pragma unroll
      for (int kk = 0; kk < 2; ++kk)
        kb[n][kk] = g_ld8(kp + n * 1024 + kk * 32);
    f32x4 sc[2][4];
    __builtin_amdgcn_s_setprio(1);
#pragma unroll
    for (int mi = 0; mi < 2; ++mi)
#pragma unroll
      for (int n = 0; n < 4; ++n) {
        sc[mi][n] = __builtin_amdgcn_mfma_f32_16x16x32_bf16(kb[n][0], bq[mi][0], zero, 0, 0, 0);
        sc[mi][n] = __builtin_amdgcn_mfma_f32_16x16x32_bf16(kb[n][1], bq[mi][1], sc[mi][n], 0, 0, 0);
      }
    __builtin_amdgcn_s_setprio(0);
    // ---- V^T fragments: issue now, consumed at PV (hidden under softmax) ----
    bf16x8 av[4][2];
    const bf16* vp = vg + kv0;
#pragma unroll
    for (int n = 0; n < 4; ++n)
#pragma unroll
      for (int kk = 0; kk < 2; ++kk)
        av[n][kk] = g_ld8(vp + n * 32768 + kk * 32);
    if (kt == nf) {   // diagonal tile: mask kv > q
#pragma unroll
      for (int mi = 0; mi < 2; ++mi) {
        const int qrow = q0 + mi * 16 + l15;
#pragma unroll
        for (int n = 0; n < 4; ++n)
#pragma unroll
          for (int r = 0; r < 4; ++r)
            if (kv0 + n * 16 + l4 * 4 + r > qrow) sc[mi][n][r] = -3.0e30f;
      }
    }
    // ---- online softmax (lane-local rows, q=l15) ----
#pragma unroll
    for (int mi = 0; mi < 2; ++mi) {
      float t0 = fmaxf(fmaxf(sc[mi][0][0], sc[mi][0][1]), fmaxf(sc[mi][0][2], sc[mi][0][3]));
      float t1 = fmaxf(fmaxf(sc[mi][1][0], sc[mi][1][1]), fmaxf(sc[mi][1][2], sc[mi][1][3]));
      float t2 = fmaxf(fmaxf(sc[mi][2][0], sc[mi][2][1]), fmaxf(sc[mi][2][2], sc[mi][2][3]));
      float t3 = fmaxf(fmaxf(sc[mi][3][0], sc[mi][3][1]), fmaxf(sc[mi][3][2], sc[mi][3][3]));
      float mx = fmaxf(fmaxf(t0, t1), fmaxf(t2, t3));
      mx = fmaxf(mx, __shfl_xor(mx, 16));
      mx = fmaxf(mx, __shfl_xor(mx, 32));
      // defer-max (T13): rescale only if max grew by > 11.5 (log2 units)
      if (!__all(mx <= m[mi] + 11.5f)) {
        const float mn = fmaxf(m[mi], mx);
        const float corr = fexp2(m[mi] - mn);
        m[mi] = mn;
        l[mi] *= corr;
#pragma unroll
        for (int n = 0; n < 4; ++n) o[mi][n] *= corr;
      }
      const float mm = m[mi];
      float pr[4][4];
#pragma unroll
      for (int n = 0; n < 4; ++n)
#pragma unroll
        for (int r = 0; r < 4; ++r) pr[n][r] = fexp2(sc[mi][n][r] - mm);
      float s0 = (pr[0][0] + pr[0][1]) + (pr[0][2] + pr[0][3]);
      float s1 = (pr[1][0] + pr[1][1]) + (pr[1][2] + pr[1][3]);
      float s2 = (pr[2][0] + pr[2][1]) + (pr[2][2] + pr[2][3]);
      float s3 = (pr[3][0] + pr[3][1]) + (pr[3][2] + pr[3][3]);
      float rs = (s0 + s1) + (s2 + s3);
      rs += __shfl_xor(rs, 16);
      rs += __shfl_xor(rs, 32);
      l[mi] += rs;
      char* base = plw + mi * 2048;
#pragma unroll
      for (int n = 0; n < 4; ++n)
        *(uint2*)(base + l15 * 128 + ((n * 32 + l4 * 8) ^ sw)) =
            pack4(pr[n][0], pr[n][1], pr[n][2], pr[n][3]);
    }
    // ---- PV: O^T += V^T * P ----
    bf16x8 pb[2][2];
#pragma unroll
    for (int mi = 0; mi < 2; ++mi)
#pragma unroll
      for (int kk = 0; kk < 2; ++kk)
        pb[mi][kk] = lds_ld8(plw + mi * 2048 + l15 * 128 + ((kk * 64 + l4 * 16) ^ sw));
    __builtin_amdgcn_s_setprio(1);
#pragma unroll
    for (int mi = 0; mi < 2; ++mi)
#pragma unroll
      for (int n = 0; n < 4; ++n) {
        o[mi][n] = __builtin_amdgcn_mfma_f32_16x16x32_bf16(av[n][0], pb[mi][0], o[mi][n], 0, 0, 0);
        o[mi][n] = __builtin_amdgcn_mfma_f32_16x16x32_bf16(av[n][1], pb[mi][1], o[mi][n], 0, 0, 0);
      }
    __builtin_amdgcn_s_setprio(0);
  }

  // ---- cross-wave merge: (m,l,o) partials -> wave 0 ----
  auto slot_write = [&](int s) {
#pragma unroll
    for (int mi = 0; mi < 2; ++mi) {
#pragma unroll
      for (int n = 0; n < 4; ++n)
#pragma unroll
        for (int j = 0; j < 4; ++j) mb[s][mi][n * 4 + j][lane] = o[mi][n][j];
      mb[s][mi][16][lane] = m[mi];
      mb[s][mi][17][lane] = l[mi];
    }
  };
  auto slot_combine = [&](int s) {
#pragma unroll
    for (int mi = 0; mi < 2; ++mi) {
      const float m2 = mb[s][mi][16][lane], l2 = mb[s][mi][17][lane];
      const float M = fmaxf(m[mi], m2);
      const float ca = fexp2(m[mi] - M), cb = fexp2(m2 - M);
      m[mi] = M;
      l[mi] = l[mi] * ca + l2 * cb;
#pragma unroll
      for (int n = 0; n < 4; ++n)
#pragma unroll
        for (int j = 0; j < 4; ++j)
          o[mi][n][j] = o[mi][n][j] * ca + mb[s][mi][n * 4 + j][lane] * cb;
    }
  };
  __syncthreads();
  if (w >= 2) slot_write(w - 2);
  __syncthreads();
  if (w < 2) slot_combine(w);
  __syncthreads();
  if (w == 1) slot_write(0);
  __syncthreads();
  if (w == 0) {
    slot_combine(0);
    // normalize + transpose via LDS (slot-1 area is free) + coalesced store
    char* ep = lds + 9216;
#pragma unroll
    for (int mi = 0; mi < 2; ++mi) {
      const float inv = 1.0f / l[mi];
      char* base = ep + mi * 2048;
#pragma unroll
      for (int n = 0; n < 4; ++n)
        *(uint2*)(base + l15 * 128 + ((n * 32 + l4 * 8) ^ sw)) =
            pack4(o[mi][n][0] * inv, o[mi][n][1] * inv, o[mi][n][2] * inv, o[mi][n][3] * inv);
#pragma unroll
      for (int kk = 0; kk < 2; ++kk) {
        uint4 val = *(const uint4*)(base + l15 * 128 + ((kk * 64 + l4 * 16) ^ sw));
        *(uint4*)(ctx + ((size_t)(b * 2048 + q0 + mi * 16 + l15)) * 2048 + h * 64 + kk * 32 + l4 * 8) = val;
      }
    }
  }
}

// ---------------- Output GEMM: ctx @ Wo -> f32 ----------------
__global__ __launch_bounds__(256) void k_gemm_out(const bf16* __restrict__ A, const bf16* __restrict__ Bt,
                                                  float* __restrict__ out) {
  __shared__ __align__(16) char ldsA[8192];
  __shared__ __align__(16) char ldsB[8192];
  const int tid = threadIdx.x;
  const int brow = blockIdx.x * 128, bcol = blockIdx.y * 128;
  f32x4 zero = {0.f, 0.f, 0.f, 0.f};
  f32x4 acc[4][4];
#pragma unroll
  for (int m = 0; m < 4; ++m)
#pragma unroll
    for (int n = 0; n < 4; ++n) acc[m][n] = zero;

  gemm_main(A, Bt, brow, bcol, tid, acc, ldsA, ldsB);

  const int lane = tid & 63, l15 = lane & 15, l4 = lane >> 4;
  const int wid = tid >> 6, wr = wid >> 1, wc = wid & 1;
#pragma unroll
  for (int m = 0; m < 4; ++m)
#pragma unroll
    for (int r = 0; r < 4; ++r) {
      const int row = brow + wr * 64 + m * 16 + l4 * 4 + r;
      float* dst = out + (size_t)row * 2048 + bcol + wc * 64;
#pragma unroll
      for (int n = 0; n < 4; ++n) dst[n * 16 + l15] = acc[m][n][r];
    }
}

extern "C" void kernel_launch(void* const* d_in, const int* in_sizes, int n_in,
                              void* d_out, int out_size, void* d_ws, size_t ws_size,
                              hipStream_t stream) {
  (void)in_sizes; (void)n_in; (void)out_size;
  if (ws_size < (size_t)79691776) return;   // need ~76 MB scratch
  const float* x    = (const float*)d_in[0];
  // d_in[1] = mask (causal, hardcoded)
  const float* cosT = (const float*)d_in[2];
  const float* sinT = (const float*)d_in[3];
  const float* Wq   = (const float*)d_in[4];
  const float* Wk   = (const float*)d_in[5];
  const float* Wv   = (const float*)d_in[6];
  const float* Wo   = (const float*)d_in[7];
  char* ws = (char*)d_ws;
  bf16* xb   = (bf16*)(ws + 0);            // [4096][2048]
  bf16* wqkv = (bf16*)(ws + 16777216);     // [3072][2048]  (Wq^T | Wk^T | Wv^T)
  bf16* wo_t = (bf16*)(ws + 29360128);     // [2048][2048]
  bf16* Qb   = (bf16*)(ws + 37748736);     // [2][32][2048][64]
  bf16* Kb   = (bf16*)(ws + 54525952);     // [2][8][2048][64]
  bf16* Vt   = (bf16*)(ws + 58720256);     // [2][8][64][2048]  (transposed V)
  bf16* ctxb = (bf16*)(ws + 62914560);     // [4096][2048]
  float* out = (float*)d_out;

  k_convert<<<8192, 256, 0, stream>>>(x, xb, 2097152);
  k_transp<<<dim3(32, 32), 256, 0, stream>>>(Wq, wqkv, 2048, 0);
  k_transp<<<dim3(8, 32),  256, 0, stream>>>(Wk, wqkv, 512, 2048);
  k_transp<<<dim3(8, 32),  256, 0, stream>>>(Wv, wqkv, 512, 2560);
  k_transp<<<dim3(32, 32), 256, 0, stream>>>(Wo, wo_t, 2048, 0);
  k_gemm_qkv<<<dim3(32, 24), 256, 0, stream>>>(xb, wqkv, cosT, sinT, Qb, Kb, Vt);
  k_attn<<<4096, 256, 0, stream>>>(Qb, Kb, Vt, ctxb);
  k_gemm_out<<<dim3(32, 16), 256, 0, stream>>>(ctxb, wo_t, out);
}

// Round 8
// 340.101 us; speedup vs baseline: 1.0081x; 1.0081x over previous
//
#include <hip/hip_runtime.h>
#include <hip/hip_bf16.h>

using bf16 = __bf16;
using bf16x8 = __attribute__((ext_vector_type(8))) __bf16;
using bf16x4 = __attribute__((ext_vector_type(4))) __bf16;
using f32x4  = __attribute__((ext_vector_type(4))) float;
using f32x16 = __attribute__((ext_vector_type(16))) float;

typedef const void __attribute__((address_space(1)))* gas_p;
typedef void __attribute__((address_space(3)))* las_p;

#define GLD16(g, l) __builtin_amdgcn_global_load_lds((gas_p)(const void*)(g), (las_p)(void*)(l), 16, 0, 0)

__device__ __forceinline__ bf16x8 lds_ld8(const void* p) {
  union { uint4 u; bf16x8 v; } c;
  c.u = *(const uint4*)p;
  return c.v;
}
__device__ __forceinline__ bf16x8 g_ld8(const bf16* p) {
  union { uint4 u; bf16x8 v; } c;
  c.u = *(const uint4*)p;
  return c.v;
}
// A-fragment via sigma k-slot permutation: two 4-bf16 chunks at p and p+8
__device__ __forceinline__ bf16x8 g_ld44(const bf16* p) {
  union { uint2 u2[2]; bf16x8 v; } c;
  c.u2[0] = *(const uint2*)p;
  c.u2[1] = *(const uint2*)(p + 8);
  return c.v;
}
// single-instruction 2^x
__device__ __forceinline__ float fexp2(float x) {
  float r; asm("v_exp_f32 %0, %1" : "=v"(r) : "v"(x)); return r;
}
// v_cvt_pk_bf16_f32: dst[15:0]=bf16(lo), dst[31:16]=bf16(hi)
__device__ __forceinline__ unsigned cvtpk(float lo, float hi) {
  unsigned r; asm("v_cvt_pk_bf16_f32 %0, %1, %2" : "=v"(r) : "v"(lo), "v"(hi)); return r;
}

// ---------------- f32 -> bf16 elementwise convert ----------------
__global__ void k_convert(const float* __restrict__ in, bf16* __restrict__ out, int n4) {
  int i = blockIdx.x * blockDim.x + threadIdx.x;
  if (i >= n4) return;
  float4 f = ((const float4*)in)[i];
  bf16x4 o;
  o[0] = (bf16)f.x; o[1] = (bf16)f.y; o[2] = (bf16)f.z; o[3] = (bf16)f.w;
  ((bf16x4*)out)[i] = o;
}

// ---------------- transpose + convert weights: W[K=2048][N] -> Wt[N][2048] bf16 ----------------
__global__ void k_transp(const float* __restrict__ W, bf16* __restrict__ Wt, int N, int rowOff) {
  __shared__ float tile[64][65];
  const int n0 = blockIdx.x * 64, k0 = blockIdx.y * 64;
  const int t = threadIdx.x;
#pragma unroll
  for (int i = 0; i < 16; ++i) {
    int idx = t + i * 256; int r = idx >> 6, c = idx & 63;
    tile[r][c] = W[(size_t)(k0 + r) * N + n0 + c];
  }
  __syncthreads();
#pragma unroll
  for (int i = 0; i < 16; ++i) {
    int idx = t + i * 256; int r = idx >> 6, c = idx & 63;
    Wt[(size_t)(rowOff + n0 + r) * 2048 + k0 + c] = (bf16)tile[c][r];
  }
}

// ---------------- GEMM main loop: C[128x128] += A[128xK] * Bt[128xK]^T, K=2048, BK=32 ----------------
__device__ __forceinline__ void gemm_main(const bf16* __restrict__ A, const bf16* __restrict__ Bt,
                                          int brow, int bcol, int tid, f32x4 (&acc)[4][4],
                                          char* ldsA, char* ldsB) {
  const int lane = tid & 63;
  const int l15 = lane & 15, l4 = lane >> 4;
  const int wid = tid >> 6, wr = wid >> 1, wc = wid & 1;
  const int srow = tid >> 2;
  const int sseg = (tid & 3) ^ (srow & 3);   // pre-swizzled global source (m173 pattern)
  const bf16* ga = A  + (size_t)(brow + srow) * 2048 + sseg * 8;
  const bf16* gb = Bt + (size_t)(bcol + srow) * 2048 + sseg * 8;
  char* la = ldsA + tid * 16;
  char* lb = ldsB + tid * 16;
  const int roff = (l15 & 3) << 4;

  for (int k0 = 0; k0 < 2048; k0 += 32) {
    __syncthreads();
    GLD16(ga + k0, la);
    GLD16(ga + k0 + (size_t)64 * 2048, la + 4096);
    GLD16(gb + k0, lb);
    GLD16(gb + k0 + (size_t)64 * 2048, lb + 4096);
    __syncthreads();
    bf16x8 af[4], bfr[4];
#pragma unroll
    for (int m = 0; m < 4; ++m)
      af[m] = lds_ld8(ldsA + (wr * 64 + m * 16 + l15) * 64 + ((l4 << 4) ^ roff));
#pragma unroll
    for (int n = 0; n < 4; ++n)
      bfr[n] = lds_ld8(ldsB + (wc * 64 + n * 16 + l15) * 64 + ((l4 << 4) ^ roff));
#pragma unroll
    for (int m = 0; m < 4; ++m)
#pragma unroll
      for (int n = 0; n < 4; ++n)
        acc[m][n] = __builtin_amdgcn_mfma_f32_16x16x32_bf16(af[m], bfr[n], acc[m][n], 0, 0, 0);
  }
}

// ---------------- QKV GEMM + RoPE epilogue (V written transposed) ----------------
// Q scale folds 1/sqrt(64) * log2(e) so attention softmax can use exp2 directly.
__global__ __launch_bounds__(256) void k_gemm_qkv(const bf16* __restrict__ A, const bf16* __restrict__ Bt,
    const float* __restrict__ cosT, const float* __restrict__ sinT,
    bf16* __restrict__ Qb, bf16* __restrict__ Kb, bf16* __restrict__ Vt) {
  __shared__ __align__(16) char ldsA[8192];
  __shared__ __align__(16) char ldsB[8192];
  const int tid = threadIdx.x;
  const int brow = blockIdx.x * 128, bcol = blockIdx.y * 128;
  f32x4 zero = {0.f, 0.f, 0.f, 0.f};
  f32x4 acc[4][4];
#pragma unroll
  for (int m = 0; m < 4; ++m)
#pragma unroll
    for (int n = 0; n < 4; ++n) acc[m][n] = zero;

  gemm_main(A, Bt, brow, bcol, tid, acc, ldsA, ldsB);

  const int lane = tid & 63, l15 = lane & 15, l4 = lane >> 4;
  const int wid = tid >> 6, wr = wid >> 1, wc = wid & 1;
  const int base64 = bcol + wc * 64;       // wave-uniform; one head per wave block
  const int rbase  = brow + wr * 64;

  if (base64 < 2048) {                      // Q segment (RoPE + 0.125*log2e scale)
    const int h = base64 >> 6;
#pragma unroll
    for (int m = 0; m < 4; ++m)
#pragma unroll
      for (int r = 0; r < 4; ++r) {
        const int row = rbase + m * 16 + l4 * 4 + r;
        const int b = row >> 11, s = row & 2047;
        float o[4];
#pragma unroll
        for (int n = 0; n < 4; ++n) {
          const int d = n * 16 + l15;
          const float cv = cosT[s * 64 + d], sv = sinT[s * 64 + d];
          const float t = acc[m][n][r], p = acc[m][n ^ 2][r];
          o[n] = (t * cv + ((n < 2) ? -p : p) * sv) * 0.18033688f;
        }
        bf16* dst = Qb + ((size_t)((b * 32 + h) * 2048 + s)) * 64;
#pragma unroll
        for (int n = 0; n < 4; ++n) dst[n * 16 + l15] = (bf16)o[n];
      }
  } else if (base64 < 2560) {               // K segment (RoPE)
    const int h = (base64 - 2048) >> 6;
#pragma unroll
    for (int m = 0; m < 4; ++m)
#pragma unroll
      for (int r = 0; r < 4; ++r) {
        const int row = rbase + m * 16 + l4 * 4 + r;
        const int b = row >> 11, s = row & 2047;
        float o[4];
#pragma unroll
        for (int n = 0; n < 4; ++n) {
          const int d = n * 16 + l15;
          const float cv = cosT[s * 64 + d], sv = sinT[s * 64 + d];
          const float t = acc[m][n][r], p = acc[m][n ^ 2][r];
          o[n] = t * cv + ((n < 2) ? -p : p) * sv;
        }
        bf16* dst = Kb + ((size_t)((b * 8 + h) * 2048 + s)) * 64;
#pragma unroll
        for (int n = 0; n < 4; ++n) dst[n * 16 + l15] = (bf16)o[n];
      }
  } else {                                  // V segment -> transposed Vt[b][hk][d][s]
    const int h = (base64 - 2560) >> 6;
#pragma unroll
    for (int m = 0; m < 4; ++m)
#pragma unroll
      for (int r = 0; r < 4; ++r) {
        const int row = rbase + m * 16 + l4 * 4 + r;
        const int b = row >> 11, s = row & 2047;
#pragma unroll
        for (int n = 0; n < 4; ++n) {
          const int d = n * 16 + l15;
          Vt[((size_t)((b * 8 + h) * 64 + d)) * 2048 + s] = (bf16)acc[m][n][r];
        }
      }
  }
}

// ---------------- Flash attention (causal, GQA), 32x32 swapped-operand ----------------
// One wave = one 32-row q chunk. sc = mfma_32x32x16(K, Q): lane holds one q-row
// (q = lane&31), kv rows (r&3)+8*(r>>2)+4*hi; partner lane^32 holds the rest.
// Softmax reduce: in-lane tree + __shfl_xor(32). PV uses a k-slot permutation
// sigma(k=hi*8+j) = (j&3)+8*(j>>2)+4*hi applied to BOTH V (addressing) and P
// (register order), so the P B-fragment is the lane's OWN sc registers packed
// with cvt_pk -> zero cross-lane traffic, zero LDS in the main loop.
__global__ __launch_bounds__(256) void k_attn(const bf16* __restrict__ Qb, const bf16* __restrict__ Kb,
                                              const bf16* __restrict__ Vt, bf16* __restrict__ ctx) {
  __shared__ __align__(16) char lds[4][4096];  // per-wave epilogue transpose buffer
  const int tid = threadIdx.x, lane = tid & 63, w = tid >> 6;
  const int l31 = lane & 31, hi = lane >> 5;
  // XCD-aware: XCD = p&7 owns 8 contiguous bh values
  const int p = (int)blockIdx.x;
  const int y = (p & 7) * 8 + ((p >> 3) & 7);   // bh
  const int xl = p >> 6;                         // 0..15
  int c;                                         // balanced chunks per block
  switch (w) { case 0: c = xl; break; case 1: c = 31 - xl; break;
               case 2: c = 32 + xl; break; default: c = 63 - xl; }
  const int q0 = c * 32, nf = c >> 1;
  const int b = y >> 5, h = y & 31, hk = h >> 2;
  char* plw = lds[w];

  const bf16* qbase = Qb + ((size_t)((b * 32 + h) * 2048) + q0 + l31) * 64 + hi * 8;
  const bf16* kbase = Kb + ((size_t)((b * 8 + hk) * 2048) + l31) * 64 + hi * 8;
  const bf16* vbase = Vt + ((size_t)((b * 8 + hk) * 64) + l31) * 2048 + hi * 4;  // sigma base

  // Q as B-fragments: col=l31 -> q, k = d = dc*16 + hi*8 + j
  bf16x8 bq[4];
#pragma unroll
  for (int dc = 0; dc < 4; ++dc) bq[dc] = g_ld8(qbase + dc * 16);

  const f32x16 z16 = {0,0,0,0,0,0,0,0,0,0,0,0,0,0,0,0};
  f32x16 o[2] = {z16, z16};   // O^T[dh]: col=q, row d = dh*32+(r&3)+8*(r>>2)+4*hi
  float m = -3.0e38f, lsum = 0.f;

  for (int kt = 0; kt <= nf; ++kt) {
    const int kv0 = kt * 64;
    // ---- K A-fragments: row = kv = kv0+kvh*32+l31, k = d ----
    bf16x8 ak[2][4];
#pragma unroll
    for (int kvh = 0; kvh < 2; ++kvh)
#pragma unroll
      for (int dc = 0; dc < 4; ++dc)
        ak[kvh][dc] = g_ld8(kbase + (size_t)(kv0 + kvh * 32) * 64 + dc * 16);
    f32x16 sc[2];
    __builtin_amdgcn_s_setprio(1);
#pragma unroll
    for (int kvh = 0; kvh < 2; ++kvh) {
      sc[kvh] = __builtin_amdgcn_mfma_f32_32x32x16_bf16(ak[kvh][0], bq[0], z16, 0, 0, 0);
#pragma unroll
      for (int dc = 1; dc < 4; ++dc)
        sc[kvh] = __builtin_amdgcn_mfma_f32_32x32x16_bf16(ak[kvh][dc], bq[dc], sc[kvh], 0, 0, 0);
    }
    __builtin_amdgcn_s_setprio(0);
    // ---- V^T A-fragments (sigma layout): row = d = dh*32+l31,
    //      slot k=hi*8+j -> kv = kv0 + cc*16 + (j&3)+8*(j>>2)+4*hi ----
    bf16x8 av[2][4];
#pragma unroll
    for (int dh = 0; dh < 2; ++dh)
#pragma unroll
      for (int cc = 0; cc < 4; ++cc)
        av[dh][cc] = g_ld44(vbase + (size_t)dh * 65536 + kv0 + cc * 16);

    if (kt == nf) {   // diagonal tile: mask kv > q
      const int q = q0 + l31;
#pragma unroll
      for (int kvh = 0; kvh < 2; ++kvh)
#pragma unroll
        for (int r = 0; r < 16; ++r) {
          const int kv = kv0 + kvh * 32 + (r & 3) + 8 * (r >> 2) + 4 * hi;
          if (kv > q) sc[kvh][r] = -3.0e30f;
        }
    }
    // ---- softmax: row in lane-pair (lane, lane^32) ----
    float mx = sc[0][0];
#pragma unroll
    for (int r = 1; r < 16; ++r) mx = fmaxf(mx, sc[0][r]);
#pragma unroll
    for (int r = 0; r < 16; ++r) mx = fmaxf(mx, sc[1][r]);
    mx = fmaxf(mx, __shfl_xor(mx, 32));
    // defer-max (T13): rescale only if max grew by > 11.5 (log2 units)
    if (!__all(mx <= m + 11.5f)) {
      const float mn = fmaxf(m, mx);
      const float corr = fexp2(m - mn);
      m = mn;
      lsum *= corr;
#pragma unroll
      for (int r = 0; r < 16; ++r) { o[0][r] *= corr; o[1][r] *= corr; }
    }
#pragma unroll
    for (int kvh = 0; kvh < 2; ++kvh)
#pragma unroll
      for (int r = 0; r < 16; ++r) sc[kvh][r] = fexp2(sc[kvh][r] - m);
    float rs = 0.f;
#pragma unroll
    for (int r = 0; r < 16; ++r) rs += sc[0][r] + sc[1][r];
    lsum += rs + __shfl_xor(rs, 32);
    // ---- PV: P B-fragment = own sc registers packed (sigma) ----
#pragma unroll
    for (int kvh = 0; kvh < 2; ++kvh) {
#pragma unroll
      for (int s = 0; s < 2; ++s) {
        union { unsigned u[4]; bf16x8 v; } f;
#pragma unroll
        for (int t = 0; t < 4; ++t)
          f.u[t] = cvtpk(sc[kvh][s * 8 + 2 * t], sc[kvh][s * 8 + 2 * t + 1]);
        __builtin_amdgcn_s_setprio(1);
#pragma unroll
        for (int dh = 0; dh < 2; ++dh)
          o[dh] = __builtin_amdgcn_mfma_f32_32x32x16_bf16(av[dh][kvh * 2 + s], f.v, o[dh], 0, 0, 0);
        __builtin_amdgcn_s_setprio(0);
      }
    }
  }

  // ---- epilogue: normalize (lane-local), transpose via per-wave LDS, store ----
  const float inv = 1.0f / lsum;
  const int sw = (l31 & 7) << 4;
#pragma unroll
  for (int dh = 0; dh < 2; ++dh)
#pragma unroll
    for (int r = 0; r < 16; r += 2) {
      const unsigned wdv = cvtpk(o[dh][r] * inv, o[dh][r + 1] * inv);
      const int d = dh * 32 + (r & 3) + 8 * (r >> 2) + 4 * hi;
      *(unsigned*)(plw + l31 * 128 + ((d * 2) ^ sw)) = wdv;
    }
  // per-wave private buffer: compiler inserts lgkmcnt; no barrier needed
#pragma unroll
  for (int j = 0; j < 4; ++j) {
    const int off = hi * 16 + j * 32;
    uint4 val = *(const uint4*)(plw + l31 * 128 + (off ^ sw));
    *(uint4*)(ctx + ((size_t)(b * 2048 + q0 + l31)) * 2048 + h * 64 + off / 2) = val;
  }
}

// ---------------- Output GEMM: ctx @ Wo -> f32 ----------------
__global__ __launch_bounds__(256) void k_gemm_out(const bf16* __restrict__ A, const bf16* __restrict__ Bt,
                                                  float* __restrict__ out) {
  __shared__ __align__(16) char ldsA[8192];
  __shared__ __align__(16) char ldsB[8192];
  const int tid = threadIdx.x;
  const int brow = blockIdx.x * 128, bcol = blockIdx.y * 128;
  f32x4 zero = {0.f, 0.f, 0.f, 0.f};
  f32x4 acc[4][4];
#pragma unroll
  for (int m = 0; m < 4; ++m)
#pragma unroll
    for (int n = 0; n < 4; ++n) acc[m][n] = zero;

  gemm_main(A, Bt, brow, bcol, tid, acc, ldsA, ldsB);

  const int lane = tid & 63, l15 = lane & 15, l4 = lane >> 4;
  const int wid = tid >> 6, wr = wid >> 1, wc = wid & 1;
#pragma unroll
  for (int m = 0; m < 4; ++m)
#pragma unroll
    for (int r = 0; r < 4; ++r) {
      const int row = brow + wr * 64 + m * 16 + l4 * 4 + r;
      float* dst = out + (size_t)row * 2048 + bcol + wc * 64;
#pragma unroll
      for (int n = 0; n < 4; ++n) dst[n * 16 + l15] = acc[m][n][r];
    }
}

extern "C" void kernel_launch(void* const* d_in, const int* in_sizes, int n_in,
                              void* d_out, int out_size, void* d_ws, size_t ws_size,
                              hipStream_t stream) {
  (void)in_sizes; (void)n_in; (void)out_size;
  if (ws_size < (size_t)79691776) return;   // need ~76 MB scratch
  const float* x    = (const float*)d_in[0];
  // d_in[1] = mask (causal, hardcoded)
  const float* cosT = (const float*)d_in[2];
  const float* sinT = (const float*)d_in[3];
  const float* Wq   = (const float*)d_in[4];
  const float* Wk   = (const float*)d_in[5];
  const float* Wv   = (const float*)d_in[6];
  const float* Wo   = (const float*)d_in[7];
  char* ws = (char*)d_ws;
  bf16* xb   = (bf16*)(ws + 0);            // [4096][2048]
  bf16* wqkv = (bf16*)(ws + 16777216);     // [3072][2048]  (Wq^T | Wk^T | Wv^T)
  bf16* wo_t = (bf16*)(ws + 29360128);     // [2048][2048]
  bf16* Qb   = (bf16*)(ws + 37748736);     // [2][32][2048][64]
  bf16* Kb   = (bf16*)(ws + 54525952);     // [2][8][2048][64]
  bf16* Vt   = (bf16*)(ws + 58720256);     // [2][8][64][2048]  (transposed V)
  bf16* ctxb = (bf16*)(ws + 62914560);     // [4096][2048]
  float* out = (float*)d_out;

  k_convert<<<8192, 256, 0, stream>>>(x, xb, 2097152);
  k_transp<<<dim3(32, 32), 256, 0, stream>>>(Wq, wqkv, 2048, 0);
  k_transp<<<dim3(8, 32),  256, 0, stream>>>(Wk, wqkv, 512, 2048);
  k_transp<<<dim3(8, 32),  256, 0, stream>>>(Wv, wqkv, 512, 2560);
  k_transp<<<dim3(32, 32), 256, 0, stream>>>(Wo, wo_t, 2048, 0);
  k_gemm_qkv<<<dim3(32, 24), 256, 0, stream>>>(xb, wqkv, cosT, sinT, Qb, Kb, Vt);
  k_attn<<<1024, 256, 0, stream>>>(Qb, Kb, Vt, ctxb);
  k_gemm_out<<<dim3(32, 16), 256, 0, stream>>>(ctxb, wo_t, out);
}